// Round 12
// baseline (38.622 us; speedup 1.0000x reference)
//
#include <hip/hip_runtime.h>
#include <hip/hip_bf16.h>

typedef __attribute__((ext_vector_type(4))) float f32x4;
typedef __attribute__((ext_vector_type(16))) float f32x16;
typedef __attribute__((ext_vector_type(8))) short bf16x8;
typedef __attribute__((ext_vector_type(4))) short bf16x4;
typedef __attribute__((ext_vector_type(4))) unsigned u32x4;

#define SEQ 2048
#define NH 4
#define DH 16

// ws layout (bytes)
#define WS_LEN 0                       // 8 * int
#define WS_WP  1024                    // 64*64 bf16
#define WS_Q   65536                   // NB*NH*SEQ*DH*2 = 2 MiB
#define WS_K   (WS_Q + 2097152)
#define WS_V   (WS_K + 2097152)        // V transposed [b][h][dh][s]

#define MFMA16 __builtin_amdgcn_mfma_f32_16x16x32_bf16
#define MFMA32 __builtin_amdgcn_mfma_f32_32x32x16_bf16

__device__ __forceinline__ short f2bf(float f){
  __hip_bfloat16 h = __float2bfloat16(f);
  return __builtin_bit_cast(short, h);
}

__device__ __forceinline__ bf16x8 pack8(f32x4 a, f32x4 b){
  bf16x8 r;
  r[0]=f2bf(a[0]); r[1]=f2bf(a[1]); r[2]=f2bf(a[2]); r[3]=f2bf(a[3]);
  r[4]=f2bf(b[0]); r[5]=f2bf(b[1]); r[6]=f2bf(b[2]); r[7]=f2bf(b[3]);
  return r;
}

// v_cvt_pk_bf16_f32: word = {hi16: bf16(b), lo16: bf16(a)}
__device__ __forceinline__ unsigned cvtpk(float a, float b){
  unsigned r;
  asm("v_cvt_pk_bf16_f32 %0, %1, %2" : "=v"(r) : "v"(a), "v"(b));
  return r;
}
// v_permlane32_swap_b32: a' = {a[0:31], b[0:31]}, b' = {a[32:63], b[32:63]}
__device__ __forceinline__ void plswap(unsigned &a, unsigned &b){
  asm volatile("v_permlane32_swap_b32 %0, %1" : "+v"(a), "+v"(b));
}

// ---------------------------------------------------------------------------
// qkv + prep fused (round-9 verbatim). grid (257,2) x 256 thr.
// ---------------------------------------------------------------------------
__global__ __launch_bounds__(256) void qkv_prep_kernel(const float* __restrict__ x,
                                                       const unsigned char* __restrict__ mask,
                                                       const float* __restrict__ wqkv,
                                                       const float* __restrict__ wproj,
                                                       unsigned char* __restrict__ ws){
  const int tid = threadIdx.x;
  if (blockIdx.x == 256){
    if (blockIdx.y == 1){
      short* wp = (short*)(ws + WS_WP);
      for (int i = tid; i < 64*64; i += 256) wp[i] = f2bf(wproj[i]);
      return;
    }
    const unsigned w0 = *(const unsigned*)mask;
    const int mode = (mask[2048] != 0) ? 0 : ((w0 == 1u) ? 1 : ((w0 == 0x3f800000u) ? 2 : 0));
    __shared__ int cnts[8];
    if (tid < 8) cnts[tid] = 0;
    __syncthreads();
    const int b = tid >> 5, j = tid & 31;
    const long long rowbase = (long long)b * SEQ * SEQ + (long long)(SEQ-1) * SEQ;
    int c = 0;
    if (mode == 0){
      const unsigned* mw = (const unsigned*)(mask + rowbase);
      for (int k = j; k < SEQ/4; k += 32){
        unsigned v = mw[k];
        c += (v & 0xffu ? 1:0) + (v & 0xff00u ? 1:0) + (v & 0xff0000u ? 1:0) + (v & 0xff000000u ? 1:0);
      }
    } else if (mode == 1){
      for (int k = j; k < SEQ; k += 32) c += ((const int*)mask)[rowbase + k] != 0;
    } else {
      for (int k = j; k < SEQ; k += 32) c += ((const float*)mask)[rowbase + k] != 0.0f;
    }
    atomicAdd(&cnts[b], c);
    __syncthreads();
    if (tid < 8) ((int*)ws)[tid] = cnts[tid];
    return;
  }

  const int lane = tid & 63;
  const int wv   = tid >> 6;
  const int c    = lane & 15;
  const int g    = lane >> 4;
  const int T0   = blockIdx.x * 64 + wv * 16;
  const f32x4 z = {0.f, 0.f, 0.f, 0.f};

  bf16x8 aw[2];
  {
    const float* xr = x + (long long)(T0 + c) * 64 + g * 8;
    #pragma unroll
    for (int w = 0; w < 2; ++w){
      f32x4 lo = *(const f32x4*)(xr + w*32);
      f32x4 hi = *(const f32x4*)(xr + w*32 + 4);
      aw[w] = pack8(lo, hi);
    }
  }

  const int tokbase = T0 + g*4;
  const int b = tokbase >> 11;
  const int sbase = tokbase & (SEQ-1);
  short* Qd = (short*)(ws + WS_Q);
  short* Kd = (short*)(ws + WS_K);
  short* Vd = (short*)(ws + WS_V);

  #pragma unroll
  for (int oi = 0; oi < 6; ++oi){
    const int ot = blockIdx.y * 6 + oi;
    const float* wr = wqkv + (ot*16 + c) * 64 + g * 8;
    bf16x8 b0 = pack8(*(const f32x4*)(wr),      *(const f32x4*)(wr + 4));
    bf16x8 b1 = pack8(*(const f32x4*)(wr + 32), *(const f32x4*)(wr + 36));
    f32x4 acc = z;
    acc = MFMA16(aw[0], b0, acc, 0, 0, 0);
    acc = MFMA16(aw[1], b1, acc, 0, 0, 0);
    if (ot < 4){
      short* dst = Qd + ((long long)(b*NH + ot) * SEQ) * DH + c;
      #pragma unroll
      for (int r = 0; r < 4; ++r)
        dst[(long long)(sbase + r) * DH] = f2bf(acc[r] * (0.25f * 1.44269504f));
    } else if (ot < 8){
      short* dst = Kd + ((long long)(b*NH + (ot-4)) * SEQ) * DH + c;
      #pragma unroll
      for (int r = 0; r < 4; ++r)
        dst[(long long)(sbase + r) * DH] = f2bf(acc[r]);
    } else {
      bf16x4 pk;
      #pragma unroll
      for (int r = 0; r < 4; ++r) pk[r] = f2bf(acc[r]);
      *(bf16x4*)(Vd + ((long long)(b*NH + (ot-8)) * DH + c) * SEQ + sbase) = pk;
    }
  }
}

// ---------------------------------------------------------------------------
// Flash attention + out-proj, fully in-register P (no P-LDS):
//  QK^T: st = MFMA32(K-frag, Q-frag) -> lane holds P[q=l&31][16 keys].
//  P -> PV A-frags: 8x cvt_pk_bf16 + 4x permlane32_swap per 32-key block
//    (chunk kc words = {swap(W0,W2).r0, swap(W1,W3).r0, .r1, .r1}).
//  PV: 4x MFMA32(A=P-frag, B=V rows) per 64-key tile; B col 16 = ones =>
//    D[q][16] = row-sum (denominator FREE in same MFMAs); cols 17-31 zero.
//  LDS: 13.3 KB (combine + ctx only). K depth-1 prefetch; V loaded at top.
// ---------------------------------------------------------------------------
__global__ __launch_bounds__(512, 4) void attn_kernel(const unsigned char* __restrict__ ws,
                                                      const float* __restrict__ bproj,
                                                      float* __restrict__ out){
  const int tid  = threadIdx.x;
  const int lane = tid & 63;
  const int wv   = tid >> 6;     // 0..7
  const int h    = wv & 3;
  const int half = wv >> 2;
  const int c    = lane & 15;
  const int g    = lane >> 4;
  const int ql   = lane & 31;    // 32x32: q for QK D; n (dh col) for PV D
  const int hi   = lane >> 5;
  const int L    = blockIdx.x;
  const int b    = (L + (L >> 8)) & 7;
  const int u    = L >> 3;
  const int t    = (u < 32) ? (2*u) : (63 - 2*(u - 32));
  const int q0   = t * 32;
  const int len  = ((const int*)ws)[b];
  const long long bh = (long long)(b*NH + h);
  const short* Q  = (const short*)(ws + WS_Q) + bh * SEQ * DH;
  const short* K  = (const short*)(ws + WS_K) + bh * SEQ * DH;
  const short* Vt = (const short*)(ws + WS_V) + bh * DH * SEQ;
  const short* Wp = (const short*)(ws + WS_WP);

  // LDS: [0,8704)     CMB f32 [4h][32q][17]
  //      [8704,9216)  LSB f32 [4h][32q]
  //      [9216,13312) CTXB bf16 [32q][64d] swizzled
  __shared__ __align__(16) unsigned char smem[13328];
  float* CMB = (float*)(smem);
  float* LSB = (float*)(smem + 8704);
  const unsigned CTXB = 9216;
  const f32x4 z  = {0.f,0.f,0.f,0.f};
  const f32x16 z16 = {0.f,0.f,0.f,0.f,0.f,0.f,0.f,0.f,0.f,0.f,0.f,0.f,0.f,0.f,0.f,0.f};
  const short one_bf = (short)0x3F80;
  const bf16x8 zs = {0,0,0,0,0,0,0,0};
  const bf16x8 ones = {one_bf,one_bf,one_bf,one_bf,one_bf,one_bf,one_bf,one_bf};

  const bf16x8 qf = *(const bf16x8*)(Q + (q0 + ql)*DH + hi*8);
  const bf16x8 constv = (ql == 16) ? ones : zs;   // B cols >=16: ones/zeros
  const bool  nlt16 = ql < 16;
  const short* vrow = Vt + (ql & 15)*SEQ;

  f32x16 accD = z16;
  const int kcount = min(q0 + 32, len);
  const int nkt  = (kcount + 63) >> 6;
  const int icnt = min(q0 >> 6, len >> 6);
  const int nh0  = nkt >> 1;
  const int kb   = half ? nh0 : 0;
  const int ke   = half ? nkt : nh0;
  const int qg   = q0 + ql;
  const unsigned sw = (unsigned)(c & 7) << 4;

  bf16x8 ka[2];
  if (kb < ke){
    const int k0 = kb * 64;
    ka[0] = *(const bf16x8*)(K + (k0 + ql)*DH + hi*8);
    ka[1] = *(const bf16x8*)(K + (k0 + 32 + ql)*DH + hi*8);
  }

  for (int kt = kb; kt < ke; ++kt){
    const int k0 = kt * 64;
    // V loads for this tile (consumed at PV, ~300cyc later)
    bf16x8 vld[4];
    #pragma unroll
    for (int cc = 0; cc < 4; ++cc)
      vld[cc] = *(const bf16x8*)(vrow + k0 + cc*16 + hi*8);
    // K prefetch (next tile)
    bf16x8 kan[2];
    if (kt + 1 < ke){
      const int k1 = k0 + 64;
      kan[0] = *(const bf16x8*)(K + (k1 + ql)*DH + hi*8);
      kan[1] = *(const bf16x8*)(K + (k1 + 32 + ql)*DH + hi*8);
    }
    const bool nomask = kt < icnt;

    const f32x16 st0 = MFMA32(ka[0], qf, z16, 0, 0, 0);
    const f32x16 st1 = MFMA32(ka[1], qf, z16, 0, 0, 0);

    #pragma unroll
    for (int kb32 = 0; kb32 < 2; ++kb32){
      const f32x16 st = kb32 ? st1 : st0;
      float p[16];
      #pragma unroll
      for (int j = 0; j < 16; ++j){
        float e = __builtin_amdgcn_exp2f(st[j]);
        if (!nomask){
          const int k = k0 + kb32*32 + (j&3) + 8*(j>>2) + 4*hi;
          e = (k <= qg && k < len) ? e : 0.f;
        }
        p[j] = e;
      }
      unsigned W[8];
      #pragma unroll
      for (int i = 0; i < 8; ++i) W[i] = cvtpk(p[2*i], p[2*i+1]);
      // chunk A = keys kb32*32 + 0..15 ; chunk B = keys kb32*32 + 16..31
      unsigned x0=W[0], y0=W[2]; plswap(x0, y0);
      unsigned x1=W[1], y1=W[3]; plswap(x1, y1);
      unsigned x2=W[4], y2=W[6]; plswap(x2, y2);
      unsigned x3=W[5], y3=W[7]; plswap(x3, y3);
      u32x4 uA = {x0, x1, y0, y1};
      u32x4 uB = {x2, x3, y2, y3};
      const bf16x8 fragA = __builtin_bit_cast(bf16x8, uA);
      const bf16x8 fragB = __builtin_bit_cast(bf16x8, uB);
      const bf16x8 vf0 = nlt16 ? vld[kb32*2 + 0] : constv;
      const bf16x8 vf1 = nlt16 ? vld[kb32*2 + 1] : constv;
      accD = MFMA32(fragA, vf0, accD, 0, 0, 0);
      accD = MFMA32(fragB, vf1, accD, 0, 0, 0);
    }
    ka[0] = kan[0]; ka[1] = kan[1];
  }

  // combine halves. accD: lane n=ql, rows q = (r&3)+8*(r>>2)+4*hi.
  if (half == 0){
    #pragma unroll
    for (int r = 0; r < 16; ++r){
      const int q = (r&3) + 8*(r>>2) + 4*hi;
      if (nlt16)        CMB[(h*32 + q)*17 + ql] = accD[r];
      else if (ql == 16) LSB[h*32 + q] = accD[r];
    }
  }
  __syncthreads();
  if (half == 1){
    #pragma unroll
    for (int r = 0; r < 16; ++r){
      const int q = (r&3) + 8*(r>>2) + 4*hi;
      const float osum = __shfl(accD[r], (lane & 32) | 16);  // own-half rowsum
      if (nlt16){
        const float tot = accD[r] + CMB[(h*32 + q)*17 + ql];
        const float lsT = LSB[h*32 + q] + osum;
        const float cv  = tot / lsT;
        *(short*)&smem[CTXB + q*128 +
            (((unsigned)((h*16 + ql)*2)) ^ ((unsigned)(q & 7) << 4))] = f2bf(cv);
      }
    }
  }
  __syncthreads();

  // out = ctx @ W_proj^T + bias; wave (h,half): o-cols h*16.., q-rows half*16..
  bf16x8 wpf[2];
  #pragma unroll
  for (int w = 0; w < 2; ++w)
    wpf[w] = *(const bf16x8*)(Wp + (h*16 + c)*64 + w*32 + g*8);
  const float bias = bproj[h*16 + c];
  f32x4 oa = z;
  const unsigned rbc = CTXB + (half*16 + c)*128;
  #pragma unroll
  for (int w = 0; w < 2; ++w){
    bf16x8 pa = *(const bf16x8*)&smem[rbc + ((unsigned)(w*64 + g*16) ^ sw)];
    oa = MFMA16(pa, wpf[w], oa, 0, 0, 0);
  }
  #pragma unroll
  for (int r = 0; r < 4; ++r)
    out[((long long)b * SEQ + q0 + half*16 + g*4 + r) * 64 + h*16 + c] = oa[r] + bias;
}

extern "C" void kernel_launch(void* const* d_in, const int* in_sizes, int n_in,
                              void* d_out, int out_size, void* d_ws, size_t ws_size,
                              hipStream_t stream) {
  const float* x     = (const float*)d_in[0];
  const unsigned char* mask = (const unsigned char*)d_in[1];
  const float* wqkv  = (const float*)d_in[2];
  const float* wproj = (const float*)d_in[3];
  const float* bproj = (const float*)d_in[4];
  float* out = (float*)d_out;
  unsigned char* ws = (unsigned char*)d_ws;

  qkv_prep_kernel<<<dim3(257, 2), 256, 0, stream>>>(x, mask, wqkv, wproj, ws);
  attn_kernel<<<512, 512, 0, stream>>>(ws, bproj, out);
}

// Round 13
// 32.112 us; speedup vs baseline: 1.2027x; 1.2027x over previous
//
#include <hip/hip_runtime.h>
#include <hip/hip_bf16.h>

typedef __attribute__((ext_vector_type(4))) float f32x4;
typedef __attribute__((ext_vector_type(16))) float f32x16;
typedef __attribute__((ext_vector_type(8))) short bf16x8;
typedef __attribute__((ext_vector_type(4))) short bf16x4;

#define SEQ 2048
#define NH 4
#define DH 16

// ws layout (bytes)
#define WS_LEN 0                       // 8 * int
#define WS_WP  1024                    // 64*64 bf16
#define WS_Q   65536                   // NB*NH*SEQ*DH*2 = 2 MiB
#define WS_K   (WS_Q + 2097152)
#define WS_V   (WS_K + 2097152)        // V transposed [b][h][dh][s]

#define MFMA16 __builtin_amdgcn_mfma_f32_16x16x32_bf16
#define MFMA32 __builtin_amdgcn_mfma_f32_32x32x16_bf16

__device__ __forceinline__ short f2bf(float f){
  __hip_bfloat16 h = __float2bfloat16(f);
  return __builtin_bit_cast(short, h);
}

__device__ __forceinline__ bf16x8 pack8(f32x4 a, f32x4 b){
  bf16x8 r;
  r[0]=f2bf(a[0]); r[1]=f2bf(a[1]); r[2]=f2bf(a[2]); r[3]=f2bf(a[3]);
  r[4]=f2bf(b[0]); r[5]=f2bf(b[1]); r[6]=f2bf(b[2]); r[7]=f2bf(b[3]);
  return r;
}

// ---------------------------------------------------------------------------
// qkv + prep fused. grid (257,2) x 256 thr.
// MFMA operands SWAPPED vs r11 (A=weight, B=x; identical loads): D col =
// token, row = output o. Q/K stores become bf16x4 (8B) per lane, the wave
// writing 512B contiguous (was 4x scalar-2B at 32B stride); V scalar stores
// now coalesce into 32B segments (was 4KB lane-stride scatter).
// ---------------------------------------------------------------------------
__global__ __launch_bounds__(256) void qkv_prep_kernel(const float* __restrict__ x,
                                                       const unsigned char* __restrict__ mask,
                                                       const float* __restrict__ wqkv,
                                                       const float* __restrict__ wproj,
                                                       unsigned char* __restrict__ ws){
  const int tid = threadIdx.x;
  if (blockIdx.x == 256){
    if (blockIdx.y == 1){
      short* wp = (short*)(ws + WS_WP);
      for (int i = tid; i < 64*64; i += 256) wp[i] = f2bf(wproj[i]);
      return;
    }
    const unsigned w0 = *(const unsigned*)mask;
    const int mode = (mask[2048] != 0) ? 0 : ((w0 == 1u) ? 1 : ((w0 == 0x3f800000u) ? 2 : 0));
    __shared__ int cnts[8];
    if (tid < 8) cnts[tid] = 0;
    __syncthreads();
    const int b = tid >> 5, j = tid & 31;
    const long long rowbase = (long long)b * SEQ * SEQ + (long long)(SEQ-1) * SEQ;
    int c = 0;
    if (mode == 0){
      const unsigned* mw = (const unsigned*)(mask + rowbase);
      for (int k = j; k < SEQ/4; k += 32){
        unsigned v = mw[k];
        c += (v & 0xffu ? 1:0) + (v & 0xff00u ? 1:0) + (v & 0xff0000u ? 1:0) + (v & 0xff000000u ? 1:0);
      }
    } else if (mode == 1){
      for (int k = j; k < SEQ; k += 32) c += ((const int*)mask)[rowbase + k] != 0;
    } else {
      for (int k = j; k < SEQ; k += 32) c += ((const float*)mask)[rowbase + k] != 0.0f;
    }
    atomicAdd(&cnts[b], c);
    __syncthreads();
    if (tid < 8) ((int*)ws)[tid] = cnts[tid];
    return;
  }

  const int lane = tid & 63;
  const int wv   = tid >> 6;
  const int c    = lane & 15;    // token lane (D col after swap)
  const int g    = lane >> 4;
  const int T0   = blockIdx.x * 64 + wv * 16;
  const f32x4 z = {0.f, 0.f, 0.f, 0.f};

  bf16x8 aw[2];
  {
    const float* xr = x + (long long)(T0 + c) * 64 + g * 8;
    #pragma unroll
    for (int w = 0; w < 2; ++w){
      f32x4 lo = *(const f32x4*)(xr + w*32);
      f32x4 hi = *(const f32x4*)(xr + w*32 + 4);
      aw[w] = pack8(lo, hi);
    }
  }

  const int tok  = T0 + c;
  const int b    = tok >> 11;
  const int s    = tok & (SEQ-1);
  short* Qd = (short*)(ws + WS_Q);
  short* Kd = (short*)(ws + WS_K);
  short* Vd = (short*)(ws + WS_V);

  #pragma unroll
  for (int oi = 0; oi < 6; ++oi){
    const int ot = blockIdx.y * 6 + oi;
    const float* wr = wqkv + (ot*16 + c) * 64 + g * 8;
    bf16x8 b0 = pack8(*(const f32x4*)(wr),      *(const f32x4*)(wr + 4));
    bf16x8 b1 = pack8(*(const f32x4*)(wr + 32), *(const f32x4*)(wr + 36));
    f32x4 acc = z;
    acc = MFMA16(b0, aw[0], acc, 0, 0, 0);   // A=weight, B=x
    acc = MFMA16(b1, aw[1], acc, 0, 0, 0);
    // D: col (lane&15) = token c, row (g*4+r) = o within ot-tile
    if (ot < 4){
      bf16x4 pk;
      #pragma unroll
      for (int r = 0; r < 4; ++r) pk[r] = f2bf(acc[r] * (0.25f * 1.44269504f));
      *(bf16x4*)(Qd + ((long long)(b*NH + ot) * SEQ + s) * DH + g*4) = pk;
    } else if (ot < 8){
      bf16x4 pk;
      #pragma unroll
      for (int r = 0; r < 4; ++r) pk[r] = f2bf(acc[r]);
      *(bf16x4*)(Kd + ((long long)(b*NH + (ot-4)) * SEQ + s) * DH + g*4) = pk;
    } else {
      #pragma unroll
      for (int r = 0; r < 4; ++r)
        Vd[((long long)(b*NH + (ot-8)) * DH + g*4 + r) * SEQ + s] = f2bf(acc[r]);
    }
  }
}

// ---------------------------------------------------------------------------
// Flash attention + out-proj (round-11 verbatim: software-pipelined P-LDS,
// MFMA-ones denominator, batch remap). r12's in-register P was SLOWER
// (serial chain, no cross-iteration overlap) — reverted.
// ---------------------------------------------------------------------------
__global__ __launch_bounds__(512, 4) void attn_kernel(const unsigned char* __restrict__ ws,
                                                      const float* __restrict__ bproj,
                                                      float* __restrict__ out){
  const int tid  = threadIdx.x;
  const int lane = tid & 63;
  const int wv   = tid >> 6;     // 0..7
  const int h    = wv & 3;
  const int half = wv >> 2;
  const int c    = lane & 15;
  const int g    = lane >> 4;
  const int ql   = lane & 31;    // 32x32 q index
  const int hi   = lane >> 5;    // 32x32 k-half
  const int L    = blockIdx.x;
  const int b    = (L + (L >> 8)) & 7;
  const int u    = L >> 3;
  const int t    = (u < 32) ? (2*u) : (63 - 2*(u - 32));
  const int q0   = t * 32;
  const int len  = ((const int*)ws)[b];
  const long long bh = (long long)(b*NH + h);
  const short* Q  = (const short*)(ws + WS_Q) + bh * SEQ * DH;
  const short* K  = (const short*)(ws + WS_K) + bh * SEQ * DH;
  const short* Vt = (const short*)(ws + WS_V) + bh * DH * SEQ;
  const short* Wp = (const short*)(ws + WS_WP);

  // LDS: [0,65536)      P double-buffer: wave wv at wv*8192, buffers +0/+4096
  //      [65536,74240)  CMB f32 [4h][32q][17]
  //      [74240,74752)  LSB f32 [4h][32q]
  //      [74752,78848)  CTXB bf16 [32q][64d] swizzled
  __shared__ __align__(16) unsigned char smem[78848];
  float* CMB = (float*)(smem + 65536);
  float* LSB = (float*)(smem + 74240);
  const unsigned pb   = (unsigned)wv * 8192;
  const unsigned CTXB = 74752;
  const f32x4 z  = {0.f,0.f,0.f,0.f};
  const f32x16 z16 = {0.f,0.f,0.f,0.f,0.f,0.f,0.f,0.f,0.f,0.f,0.f,0.f,0.f,0.f,0.f,0.f};
  const short one_bf = (short)0x3F80;   // bf16 1.0
  const bf16x8 ones = {one_bf,one_bf,one_bf,one_bf,one_bf,one_bf,one_bf,one_bf};

  const bf16x8 qf = *(const bf16x8*)(Q + (q0 + ql)*DH + hi*8);

  f32x4 acc[2]  = {z, z};
  f32x4 accS[2] = {z, z};
  const int kcount = min(q0 + 32, len);
  const int nkt  = (kcount + 63) >> 6;
  const int icnt = min(q0 >> 6, len >> 6);
  const int nh0  = nkt >> 1;
  const int kb   = half ? nh0 : 0;
  const int ke   = half ? nkt : nh0;
  const int qg   = q0 + ql;
  const unsigned swq  = (unsigned)(ql & 7) << 4;
  const unsigned sw   = (unsigned)(c & 7) << 4;

  auto qkexp = [&](int tt, bf16x8 (&kk)[2]){
    const int k0 = tt * 64;
    const bool nomask = tt < icnt;
    const unsigned rowb = pb + ((unsigned)(tt & 1) << 12) + (unsigned)ql*128;
    #pragma unroll
    for (int kb32 = 0; kb32 < 2; ++kb32){
      f32x16 st = MFMA32(kk[kb32], qf, z16, 0, 0, 0);
      #pragma unroll
      for (int grp = 0; grp < 4; ++grp){
        const int keybase = kb32*32 + grp*8 + hi*4;
        float p0 = __builtin_amdgcn_exp2f(st[grp*4 + 0]);
        float p1 = __builtin_amdgcn_exp2f(st[grp*4 + 1]);
        float p2 = __builtin_amdgcn_exp2f(st[grp*4 + 2]);
        float p3 = __builtin_amdgcn_exp2f(st[grp*4 + 3]);
        if (!nomask){
          const int k = k0 + keybase;
          p0 = (k   <= qg && k   < len) ? p0 : 0.f;
          p1 = (k+1 <= qg && k+1 < len) ? p1 : 0.f;
          p2 = (k+2 <= qg && k+2 < len) ? p2 : 0.f;
          p3 = (k+3 <= qg && k+3 < len) ? p3 : 0.f;
        }
        uint2 pk;
        pk.x = __builtin_amdgcn_perm(__builtin_bit_cast(unsigned, p1),
                                     __builtin_bit_cast(unsigned, p0), 0x07060302u);
        pk.y = __builtin_amdgcn_perm(__builtin_bit_cast(unsigned, p3),
                                     __builtin_bit_cast(unsigned, p2), 0x07060302u);
        *(uint2*)&smem[rowb + ((unsigned)(keybase*2) ^ swq)] = pk;
      }
    }
  };

  bf16x8 knx[2], vcur[2], vnx[2], knn[2], vnn[2];
  if (kb < ke){
    const int k0 = kb * 64;
    bf16x8 k0f[2];
    k0f[0] = *(const bf16x8*)(K + (k0 + ql)*DH + hi*8);
    k0f[1] = *(const bf16x8*)(K + (k0 + 32 + ql)*DH + hi*8);
    vcur[0] = *(const bf16x8*)(Vt + c*SEQ + k0 + g*8);
    vcur[1] = *(const bf16x8*)(Vt + c*SEQ + k0 + 32 + g*8);
    qkexp(kb, k0f);
    if (kb + 1 < ke){
      const int k1 = k0 + 64;
      knx[0] = *(const bf16x8*)(K + (k1 + ql)*DH + hi*8);
      knx[1] = *(const bf16x8*)(K + (k1 + 32 + ql)*DH + hi*8);
      vnx[0] = *(const bf16x8*)(Vt + c*SEQ + k1 + g*8);
      vnx[1] = *(const bf16x8*)(Vt + c*SEQ + k1 + 32 + g*8);
    }
  }

  for (int kt = kb; kt < ke; ++kt){
    // 1) PV reads of tile kt (writes completed last iteration)
    const unsigned bufr = pb + ((unsigned)(kt & 1) << 12);
    bf16x8 pa[2][2];
    #pragma unroll
    for (int qb = 0; qb < 2; ++qb)
      #pragma unroll
      for (int w = 0; w < 2; ++w)
        pa[qb][w] = *(const bf16x8*)&smem[bufr + (qb*16 + c)*128 + ((unsigned)(w*64 + g*16) ^ sw)];

    // 2) produce P(kt+1) + prefetch K/V(kt+2)
    if (kt + 1 < ke){
      if (kt + 2 < ke){
        const int k2 = (kt + 2) * 64;
        knn[0] = *(const bf16x8*)(K + (k2 + ql)*DH + hi*8);
        knn[1] = *(const bf16x8*)(K + (k2 + 32 + ql)*DH + hi*8);
        vnn[0] = *(const bf16x8*)(Vt + c*SEQ + k2 + g*8);
        vnn[1] = *(const bf16x8*)(Vt + c*SEQ + k2 + 32 + g*8);
      }
      qkexp(kt + 1, knx);
    }

    // 3) PV + rowsum MFMAs of tile kt
    #pragma unroll
    for (int qb = 0; qb < 2; ++qb)
      #pragma unroll
      for (int w = 0; w < 2; ++w){
        acc[qb]  = MFMA16(pa[qb][w], vcur[w], acc[qb], 0, 0, 0);
        accS[qb] = MFMA16(pa[qb][w], ones,    accS[qb], 0, 0, 0);
      }

    vcur[0] = vnx[0]; vcur[1] = vnx[1];
    knx[0] = knn[0]; knx[1] = knn[1];
    vnx[0] = vnn[0]; vnx[1] = vnn[1];
  }

  // combine halves: accS rows align with acc rows (q = qb*16 + g*4 + r)
  if (half == 0){
    #pragma unroll
    for (int qb = 0; qb < 2; ++qb){
      #pragma unroll
      for (int r = 0; r < 4; ++r)
        CMB[(h*32 + qb*16 + g*4 + r)*17 + c] = acc[qb][r];
      if (c == 0){
        #pragma unroll
        for (int r = 0; r < 4; ++r)
          LSB[h*32 + qb*16 + g*4 + r] = accS[qb][r];
      }
    }
  }
  __syncthreads();
  if (half == 1){
    #pragma unroll
    for (int qb = 0; qb < 2; ++qb){
      #pragma unroll
      for (int r = 0; r < 4; ++r){
        const int q = qb*16 + g*4 + r;
        const float tot = acc[qb][r] + CMB[(h*32 + q)*17 + c];
        const float lsT = LSB[h*32 + q] + accS[qb][r];
        const float cv  = tot / lsT;
        *(short*)&smem[CTXB + q*128 +
            (((unsigned)((h*16 + c)*2)) ^ ((unsigned)(q & 7) << 4))] = f2bf(cv);
      }
    }
  }
  __syncthreads();

  // out = ctx @ W_proj^T + bias; wave (h,half): o-cols h*16.., q-rows half*16..
  bf16x8 wpf[2];
  #pragma unroll
  for (int w = 0; w < 2; ++w)
    wpf[w] = *(const bf16x8*)(Wp + (h*16 + c)*64 + w*32 + g*8);
  const float bias = bproj[h*16 + c];
  f32x4 oa = z;
  const unsigned rbc = CTXB + (half*16 + c)*128;
  #pragma unroll
  for (int w = 0; w < 2; ++w){
    bf16x8 pa = *(const bf16x8*)&smem[rbc + ((unsigned)(w*64 + g*16) ^ sw)];
    oa = MFMA16(pa, wpf[w], oa, 0, 0, 0);
  }
  #pragma unroll
  for (int r = 0; r < 4; ++r)
    out[((long long)b * SEQ + q0 + half*16 + g*4 + r) * 64 + h*16 + c] = oa[r] + bias;
}

extern "C" void kernel_launch(void* const* d_in, const int* in_sizes, int n_in,
                              void* d_out, int out_size, void* d_ws, size_t ws_size,
                              hipStream_t stream) {
  const float* x     = (const float*)d_in[0];
  const unsigned char* mask = (const unsigned char*)d_in[1];
  const float* wqkv  = (const float*)d_in[2];
  const float* wproj = (const float*)d_in[3];
  const float* bproj = (const float*)d_in[4];
  float* out = (float*)d_out;
  unsigned char* ws = (unsigned char*)d_ws;

  qkv_prep_kernel<<<dim3(257, 2), 256, 0, stream>>>(x, mask, wqkv, wproj, ws);
  attn_kernel<<<512, 512, 0, stream>>>(ws, bproj, out);
}